// Round 2
// baseline (1143.377 us; speedup 1.0000x reference)
//
#include <hip/hip_runtime.h>
#include <hip/hip_bf16.h>
#include <stdint.h>

// Problem constants (B=2, N=512, DIM=INNER=EDGE_DIM=256, H=8, DH=32)
#define NB 2
#define NN 512
#define NDIM 256
#define NH 8
#define NDH 32
#define SCALE 0.17677669529663687f  // 32^-0.5

// ---------------------------------------------------------------------------
// K1: per-row projections (all f32).
//  q  = nodes@Wq+bq           (f32, [row][256])
//  k,v= nodes@Wkv+bkv split   (f32, [row][256] each)
//  qe[row][h][c] = sum_d q[row][h*32+d] * We[c][h*32+d]   (f32, [row][8][256])
//  qbe[row][h]   = sum_d q[row][h*32+d] * be[h*32+d]
// ---------------------------------------------------------------------------
__global__ __launch_bounds__(256) void k_proj(
    const float* __restrict__ nodes, const float* __restrict__ Wq, const float* __restrict__ bq,
    const float* __restrict__ Wkv, const float* __restrict__ bkv,
    const float* __restrict__ We, const float* __restrict__ be,
    float* __restrict__ q, float* __restrict__ k, float* __restrict__ v,
    float* __restrict__ qe, float* __restrict__ qbe)
{
    const int row = blockIdx.x;      // b*N + n
    const int t = threadIdx.x;
    __shared__ float xs[NDIM];
    __shared__ float qs[NDIM];
    xs[t] = nodes[(size_t)row*NDIM + t];
    __syncthreads();

    float accq = bq[t];
    float acck = bkv[t];
    float accv = bkv[t + NDIM];
    #pragma unroll 4
    for (int d = 0; d < NDIM; ++d) {
        float x = xs[d];
        accq += x * Wq[(size_t)d*NDIM + t];
        acck += x * Wkv[(size_t)d*2*NDIM + t];
        accv += x * Wkv[(size_t)d*2*NDIM + t + NDIM];
    }
    q[(size_t)row*NDIM + t] = accq;
    k[(size_t)row*NDIM + t] = acck;
    v[(size_t)row*NDIM + t] = accv;
    qs[t] = accq;
    __syncthreads();

    // qe: thread t owns We row c=t (contiguous 1KB -> float4 loads)
    float qacc[NH];
    #pragma unroll
    for (int h = 0; h < NH; ++h) qacc[h] = 0.f;
    const float* wrow = We + (size_t)t*NDIM;
    #pragma unroll
    for (int h = 0; h < NH; ++h) {
        float a0 = 0.f, a1 = 0.f, a2 = 0.f, a3 = 0.f;
        #pragma unroll
        for (int d4 = 0; d4 < NDH/4; ++d4) {
            float4 w4 = *(const float4*)(wrow + h*NDH + d4*4);
            const float* qp = qs + h*NDH + d4*4;
            a0 += qp[0]*w4.x; a1 += qp[1]*w4.y; a2 += qp[2]*w4.z; a3 += qp[3]*w4.w;
        }
        qacc[h] = (a0+a1)+(a2+a3);
    }
    #pragma unroll
    for (int h = 0; h < NH; ++h) qe[((size_t)row*NH + h)*NDIM + t] = qacc[h];
    if (t < NH) {
        float a = 0.f;
        #pragma unroll 4
        for (int d = 0; d < NDH; ++d) a += qs[t*NDH + d]*be[t*NDH + d];
        qbe[(size_t)row*NH + t] = a;
    }
}

// ---------------------------------------------------------------------------
// K3: fused edge-attention per (b,i) row. Online softmax over j in chunks of 32.
//  sim[h][j] = SCALE*( q.k + edges[b,i,j,:].qe[h] + qbe[h] )
//  w[h][c]  += p[h][j]*edges[b,i,j,c]   (one owner thread per (h,c) -> 8 regs)
//  ov[c]    += p[h(c)][j]*v[b,j,c]
//  epilogue: oi = (ov + We^T w)/l + be ; out = oi@Wo + bo  (f32 store)
// ---------------------------------------------------------------------------
__global__ __launch_bounds__(256) void k_attn(
    const float* __restrict__ edges,
    const float* __restrict__ We, const float* __restrict__ be,
    const float* __restrict__ Wo, const float* __restrict__ bo,
    const float* __restrict__ q, const float* __restrict__ k, const float* __restrict__ v,
    const float* __restrict__ qe, const float* __restrict__ qbe,
    float* __restrict__ out)
{
    const int row = blockIdx.x;        // b*N + i
    const int b = row >> 9;            // N = 512
    const int t = threadIdx.x;
    // phase-1 mapping: gA = c-block (8 floats), sA = j-stride
    const int gA = t & 31, sA = t >> 5;
    // phase-2 mapping: jlB = j within chunk, hB = head (half-wave uniform)
    const int jlB = t & 31, hB = t >> 5;
    // phase-3 mapping: hC = head, cbC = c-block
    const int hC = t & 7,  cbC = t >> 3;
    const bool isv = (hC == (cbC >> 2));   // this thread also owns ov for its c-slice

    // redbuf flat index jl*293 + g*9 + h: odd strides -> ~2-way LDS banks both phases
    __shared__ float redbuf[32*293];
    __shared__ float pbuf[256];            // [jl][h]
    __shared__ float mh[8], lh[8], al[8];
    __shared__ float wfull[2048];          // [h][c]
    __shared__ float ovfull[256];
    __shared__ float oibuf[256];

    // persistent: qe fragment, 8 heads x 8 c  (64 VGPRs)
    float qe_r[8][8];
    {
        const float* qp = qe + ((size_t)row*NH)*NDIM + gA*8;
        #pragma unroll
        for (int h = 0; h < 8; ++h) {
            float4 a0 = *(const float4*)(qp + h*NDIM);
            float4 a1 = *(const float4*)(qp + h*NDIM + 4);
            qe_r[h][0]=a0.x; qe_r[h][1]=a0.y; qe_r[h][2]=a0.z; qe_r[h][3]=a0.w;
            qe_r[h][4]=a1.x; qe_r[h][5]=a1.y; qe_r[h][6]=a1.z; qe_r[h][7]=a1.w;
        }
    }
    const float qbeV = qbe[(size_t)row*NH + hB];
    float w_r[8], ov_r[8];
    #pragma unroll
    for (int r = 0; r < 8; ++r) { w_r[r] = 0.f; ov_r[r] = 0.f; }
    if (t < 8) { mh[t] = -1e30f; lh[t] = 0.f; }
    __syncthreads();

    const float* Erow = edges + (size_t)row*NN*NDIM;
    const float* qrow = q + (size_t)row*NDIM + hB*NDH;
    const float* krow = k + ((size_t)b*NN)*NDIM + hB*NDH;

    for (int jc = 0; jc < 16; ++jc) {
        const int j0 = jc*32;
        // ---- phase 1: partial dots edges.qe (each E element read once) ----
        float4 ea[4], eb4[4];
        #pragma unroll
        for (int m = 0; m < 4; ++m) {
            const int jl = sA + m*8;
            const float* ep = Erow + (size_t)(j0+jl)*NDIM + gA*8;
            ea[m]  = *(const float4*)(ep);
            eb4[m] = *(const float4*)(ep + 4);
        }
        #pragma unroll
        for (int m = 0; m < 4; ++m) {
            const int jl = sA + m*8;
            float e[8];
            e[0]=ea[m].x; e[1]=ea[m].y; e[2]=ea[m].z; e[3]=ea[m].w;
            e[4]=eb4[m].x; e[5]=eb4[m].y; e[6]=eb4[m].z; e[7]=eb4[m].w;
            float sp[8];
            #pragma unroll
            for (int h = 0; h < 8; ++h) sp[h] = 0.f;
            #pragma unroll
            for (int c = 0; c < 8; ++c) {
                const float ec = e[c];
                #pragma unroll
                for (int h = 0; h < 8; ++h) sp[h] += qe_r[h][c]*ec;
            }
            float* rb = redbuf + jl*293 + gA*9;
            #pragma unroll
            for (int h = 0; h < 8; ++h) rb[h] = sp[h];
        }
        __syncthreads();
        // ---- phase 2: reduce, add q.k, online-softmax update ----
        {
            const int j = j0 + jlB;
            const float* kp = krow + (size_t)j*NDIM;
            float d0=0.f,d1=0.f,d2=0.f,d3=0.f;
            #pragma unroll
            for (int u = 0; u < 8; ++u) {
                float4 kv4 = *(const float4*)(kp + u*4);
                float4 qv4 = *(const float4*)(qrow + u*4);
                d0 += qv4.x*kv4.x; d1 += qv4.y*kv4.y;
                d2 += qv4.z*kv4.z; d3 += qv4.w*kv4.w;
            }
            const float* rb = redbuf + jlB*293 + hB;
            float r0=0.f,r1=0.f,r2=0.f,r3=0.f;
            #pragma unroll
            for (int g = 0; g < 32; g += 4) {
                r0 += rb[(g+0)*9]; r1 += rb[(g+1)*9];
                r2 += rb[(g+2)*9]; r3 += rb[(g+3)*9];
            }
            const float sim = SCALE*(((d0+d1)+(d2+d3)) + qbeV + ((r0+r1)+(r2+r3)));
            // butterfly over the 32 lanes of this half-wave (same hB)
            float cm = sim;
            #pragma unroll
            for (int off = 16; off >= 1; off >>= 1)
                cm = fmaxf(cm, __shfl_xor(cm, off, 64));
            const float mold = mh[hB];
            const float mnew = fmaxf(mold, cm);
            const float a_ = __expf(mold - mnew);
            const float p = __expf(sim - mnew);
            float ps = p;
            #pragma unroll
            for (int off = 16; off >= 1; off >>= 1)
                ps += __shfl_xor(ps, off, 64);
            if (jlB == 0) {           // lane 0 of half-wave; lockstep => no race
                mh[hB] = mnew;
                lh[hB] = lh[hB]*a_ + ps;
                al[hB] = a_;
            }
            pbuf[jlB*8 + hB] = p;
        }
        __syncthreads();
        // ---- phase 3: rescale + accumulate w (edges again; L2 hit) and ov ----
        {
            const float a_ = al[hC];
            #pragma unroll
            for (int r = 0; r < 8; ++r) w_r[r] *= a_;
            if (isv) {
                #pragma unroll
                for (int r = 0; r < 8; ++r) ov_r[r] *= a_;
            }
            const float* eb = Erow + (size_t)j0*NDIM + cbC*8;
            const float* vb = v + ((size_t)b*NN + j0)*NDIM + cbC*8;
            #pragma unroll 4
            for (int jl = 0; jl < 32; ++jl) {
                const float p = pbuf[jl*8 + hC];
                float4 e0 = *(const float4*)(eb + (size_t)jl*NDIM);
                float4 e1 = *(const float4*)(eb + (size_t)jl*NDIM + 4);
                w_r[0] += p*e0.x; w_r[1] += p*e0.y; w_r[2] += p*e0.z; w_r[3] += p*e0.w;
                w_r[4] += p*e1.x; w_r[5] += p*e1.y; w_r[6] += p*e1.z; w_r[7] += p*e1.w;
                if (isv) {
                    float4 v0 = *(const float4*)(vb + (size_t)jl*NDIM);
                    float4 v1 = *(const float4*)(vb + (size_t)jl*NDIM + 4);
                    ov_r[0] += p*v0.x; ov_r[1] += p*v0.y; ov_r[2] += p*v0.z; ov_r[3] += p*v0.w;
                    ov_r[4] += p*v1.x; ov_r[5] += p*v1.y; ov_r[6] += p*v1.z; ov_r[7] += p*v1.w;
                }
            }
        }
        __syncthreads();   // pbuf reuse guarded by the phase-1 barrier next iter
    }

    // ---- epilogue ----
    #pragma unroll
    for (int r = 0; r < 8; ++r) wfull[hC*NDIM + cbC*8 + r] = w_r[r];
    if (isv) {
        #pragma unroll
        for (int r = 0; r < 8; ++r) ovfull[cbC*8 + r] = ov_r[r];
    }
    __syncthreads();
    {
        const int u = t, hu = u >> 5;
        const float linv = 1.f/lh[hu];
        const float* wrow = wfull + hu*NDIM;
        float a0=0.f,a1=0.f,a2=0.f,a3=0.f;
        #pragma unroll 2
        for (int c = 0; c < NDIM; c += 4) {
            a0 += wrow[c+0]*We[(size_t)(c+0)*NDIM + u];
            a1 += wrow[c+1]*We[(size_t)(c+1)*NDIM + u];
            a2 += wrow[c+2]*We[(size_t)(c+2)*NDIM + u];
            a3 += wrow[c+3]*We[(size_t)(c+3)*NDIM + u];
        }
        oibuf[u] = (ovfull[u] + ((a0+a1)+(a2+a3)))*linv + be[u];
    }
    __syncthreads();
    {
        const int u = t;
        float a0=bo[u],a1=0.f,a2=0.f,a3=0.f;
        #pragma unroll 2
        for (int x = 0; x < NDIM; x += 4) {
            a0 += oibuf[x+0]*Wo[(size_t)(x+0)*NDIM + u];
            a1 += oibuf[x+1]*Wo[(size_t)(x+1)*NDIM + u];
            a2 += oibuf[x+2]*Wo[(size_t)(x+2)*NDIM + u];
            a3 += oibuf[x+3]*Wo[(size_t)(x+3)*NDIM + u];
        }
        out[(size_t)row*NDIM + u] = (a0+a1)+(a2+a3);
    }
}

extern "C" void kernel_launch(void* const* d_in, const int* in_sizes, int n_in,
                              void* d_out, int out_size, void* d_ws, size_t ws_size,
                              hipStream_t stream) {
    const float* nodes = (const float*)d_in[0];
    const float* edges = (const float*)d_in[1];
    const float* Wq  = (const float*)d_in[2];
    const float* bq  = (const float*)d_in[3];
    const float* Wkv = (const float*)d_in[4];
    const float* bkv = (const float*)d_in[5];
    const float* We  = (const float*)d_in[6];
    const float* be  = (const float*)d_in[7];
    const float* Wo  = (const float*)d_in[8];
    const float* bo  = (const float*)d_in[9];
    (void)in_sizes; (void)n_in; (void)out_size; (void)ws_size;

    float* ws  = (float*)d_ws;
    float* q   = ws;                       // 2*512*256          = 262144 f32
    float* k   = q  + 262144;              // 262144
    float* v   = k  + 262144;              // 262144
    float* qe  = v  + 262144;              // 2*512*8*256        = 2097152
    float* qbe = qe + 2097152;             // 2*512*8            = 8192
    // total ~11.6 MB of d_ws

    k_proj<<<dim3(NB*NN), dim3(256), 0, stream>>>(nodes, Wq, bq, Wkv, bkv, We, be,
                                                  q, k, v, qe, qbe);
    k_attn<<<dim3(NB*NN), dim3(256), 0, stream>>>(edges, We, be, Wo, bo,
                                                  q, k, v, qe, qbe,
                                                  (float*)d_out);
}